// Round 3
// baseline (297.532 us; speedup 1.0000x reference)
//
#include <hip/hip_runtime.h>

#define B_  64
#define T_  1024
#define FC_ 256
#define FX_ 512

typedef __bf16 bf16x8 __attribute__((ext_vector_type(8)));
typedef float  f32x4  __attribute__((ext_vector_type(4)));

__device__ __forceinline__ unsigned short f2bf(float f) {
  union { float f; unsigned int u; } v; v.f = f;
  unsigned int r = v.u + 0x7fffu + ((v.u >> 16) & 1u);  // RNE
  return (unsigned short)(r >> 16);
}
__device__ __forceinline__ unsigned int pk2(float lo, float hi) {
  return (unsigned int)f2bf(lo) | ((unsigned int)f2bf(hi) << 16);
}
__device__ __forceinline__ uint4 pk8(float4 a, float4 b) {
  uint4 p;
  p.x = pk2(a.x, a.y); p.y = pk2(a.z, a.w);
  p.z = pk2(b.x, b.y); p.w = pk2(b.z, b.w);
  return p;
}

// ---------------------------------------------------------------------------
// Prep: W f32 [256][512] -> bf16 ws; also zero the scalar output.
// ---------------------------------------------------------------------------
__global__ void k_wcvt(const float* __restrict__ W, unsigned short* __restrict__ Wb,
                       float* __restrict__ out) {
  const int i = blockIdx.x * 256 + threadIdx.x;   // 32768 float4-groups
  float4 v = ((const float4*)W)[i];
  ushort4 h;
  h.x = f2bf(v.x); h.y = f2bf(v.y); h.z = f2bf(v.z); h.w = f2bf(v.w);
  ((ushort4*)Wb)[i] = h;
  if (i == 0) out[0] = 0.f;
}

// ---------------------------------------------------------------------------
// Fused, one block (256 thr / 4 waves) per t. LDS = 40 KB -> 4 blocks/CU.
//   GEMM1: Xt_t = X_t * W^T + b  (64x256, K=512).  X: depth-2 reg prefetch ->
//          single 8 KB swizzled LDS buffer. W: B-frags straight from L2 (bf16).
//          Wave w owns Xt cols [64w, 64w+64) as 4 n2-frags; acc[4][4].
//   GEMM2: Z = C_t * Xt_t^T (64x64, K=256). C: A-frags straight from global,
//          f32->bf16 in-reg. Xt via 32 KB swizzled sXt (cross-wave shuffle).
//   Fused row-lse + diag + atomicAdd.
// ---------------------------------------------------------------------------
__global__ __launch_bounds__(256, 4)
void k_fused(const float* __restrict__ C, const float* __restrict__ X,
             const unsigned short* __restrict__ Wb, const float* __restrict__ bias,
             float* __restrict__ out)
{
  __shared__ __align__(16) char sMem[40960];
  char* sX  = sMem;          // 64 rows x 128 B (bf16 X chunk, swizzled)
  char* sXt = sMem + 8192;   // 64 rows x 512 B (bf16 Xt_t, swizzled)

  const int t    = blockIdx.x;
  const int tid  = threadIdx.x;
  const int lane = tid & 63;
  const int wid  = tid >> 6;      // 0..3
  const int l15  = lane & 15;
  const int lhi  = lane >> 4;     // 0..3

  // ---- X staging map: thread -> (row = tid>>2, 16 f32 at col (tid&3)*16) ----
  const int xrow = tid >> 2;
  const int xcb  = (tid & 3) * 32;              // byte col base in bf16 row
  const float* xptr = X + ((size_t)xrow * T_ + t) * FX_ + ((tid & 3) << 4);
  const int xwbase = xrow * 128;
  const int xsw    = (xrow & 7) << 4;

  // ---- W fragment base: row = wid*64 + n2*16 + l15 (1024 B rows) ----
  const char* wbase = (const char*)Wb + (size_t)(wid * 64 + l15) * 1024 + lhi * 16;

  float bv[4];
  #pragma unroll
  for (int n2 = 0; n2 < 4; ++n2) bv[n2] = bias[wid * 64 + n2 * 16 + l15];

  // ---- prologue: chunk0 -> LDS, chunk1 -> regs ----
  float4 xb[4];
  {
    float4 xa[4];
    #pragma unroll
    for (int q = 0; q < 4; ++q) xa[q] = *(const float4*)(xptr + q * 4);
    #pragma unroll
    for (int q = 0; q < 4; ++q) xb[q] = *(const float4*)(xptr + 64 + q * 4);
    uint4 p0 = pk8(xa[0], xa[1]);
    uint4 p1 = pk8(xa[2], xa[3]);
    *(uint4*)(sX + xwbase + ((xcb +  0) ^ xsw)) = p0;
    *(uint4*)(sX + xwbase + ((xcb + 16) ^ xsw)) = p1;
  }

  f32x4 acc[4][4];
  #pragma unroll
  for (int i = 0; i < 4; ++i)
    #pragma unroll
    for (int n2 = 0; n2 < 4; ++n2)
      #pragma unroll
      for (int r = 0; r < 4; ++r) acc[i][n2][r] = 0.f;

  __syncthreads();

  // ---- GEMM1 main loop, fully unrolled (8 chunks of K=64) ----
  #pragma unroll
  for (int k = 0; k < 8; ++k) {
    #pragma unroll
    for (int kk = 0; kk < 2; ++kk) {
      bf16x8 afr[4];
      #pragma unroll
      for (int i = 0; i < 4; ++i) {
        const int ar = i * 16 + l15;
        afr[i] = *(const bf16x8*)(sX + ar * 128 + ((kk * 64 + lhi * 16) ^ ((ar & 7) << 4)));
      }
      #pragma unroll
      for (int n2 = 0; n2 < 4; ++n2) {
        bf16x8 w = *(const bf16x8*)(wbase + n2 * 16384 + k * 128 + kk * 64);
        #pragma unroll
        for (int i = 0; i < 4; ++i)
          acc[i][n2] = __builtin_amdgcn_mfma_f32_16x16x32_bf16(afr[i], w, acc[i][n2], 0, 0, 0);
      }
    }
    __syncthreads();
    if (k < 7) {
      float4 xn[4];
      if (k < 6) {
        #pragma unroll
        for (int q = 0; q < 4; ++q) xn[q] = *(const float4*)(xptr + (k + 2) * 64 + q * 4);
      }
      uint4 p0 = pk8(xb[0], xb[1]);
      uint4 p1 = pk8(xb[2], xb[3]);
      *(uint4*)(sX + xwbase + ((xcb +  0) ^ xsw)) = p0;
      *(uint4*)(sX + xwbase + ((xcb + 16) ^ xsw)) = p1;
      __syncthreads();
      if (k < 6) {
        #pragma unroll
        for (int q = 0; q < 4; ++q) xb[q] = xn[q];
      }
    }
  }

  // ---- epilogue: issue C batch1, write Xt(+bias) -> sXt ----
  const float* cptr = C + ((size_t)(wid * 16 + l15) * T_ + t) * FC_ + lhi * 8;
  float4 cv[8];
  #pragma unroll
  for (int q = 0; q < 4; ++q) {
    cv[2 * q]     = *(const float4*)(cptr + q * 32);
    cv[2 * q + 1] = *(const float4*)(cptr + q * 32 + 4);
  }

  #pragma unroll
  for (int i = 0; i < 4; ++i)
    #pragma unroll
    for (int n2 = 0; n2 < 4; ++n2) {
      const int c2 = (wid * 64 + n2 * 16 + l15) * 2;
      #pragma unroll
      for (int r = 0; r < 4; ++r) {
        const int j = i * 16 + lhi * 4 + r;
        *(unsigned short*)(sXt + j * 512 + (c2 ^ ((j & 7) << 4))) =
            f2bf(acc[i][n2][r] + bv[n2]);
      }
    }

  bf16x8 ca[4];
  #pragma unroll
  for (int q = 0; q < 4; ++q) ca[q] = __builtin_bit_cast(bf16x8, pk8(cv[2 * q], cv[2 * q + 1]));
  float4 cw[8];
  #pragma unroll
  for (int q = 0; q < 4; ++q) {
    cw[2 * q]     = *(const float4*)(cptr + 128 + q * 32);
    cw[2 * q + 1] = *(const float4*)(cptr + 128 + q * 32 + 4);
  }
  __syncthreads();

  // ---- GEMM2: z[n] over K=256 in 8 slices; wave wid = Z rows 16wid.. ----
  f32x4 z[4];
  #pragma unroll
  for (int n = 0; n < 4; ++n)
    #pragma unroll
    for (int r = 0; r < 4; ++r) z[n][r] = 0.f;

  #pragma unroll
  for (int q = 0; q < 4; ++q) {
    #pragma unroll
    for (int n = 0; n < 4; ++n) {
      const int br = n * 16 + l15;
      bf16x8 b = *(const bf16x8*)(sXt + br * 512 + ((q * 64 + lhi * 16) ^ ((br & 7) << 4)));
      z[n] = __builtin_amdgcn_mfma_f32_16x16x32_bf16(ca[q], b, z[n], 0, 0, 0);
    }
  }
  #pragma unroll
  for (int q = 0; q < 4; ++q) ca[q] = __builtin_bit_cast(bf16x8, pk8(cw[2 * q], cw[2 * q + 1]));
  #pragma unroll
  for (int q = 0; q < 4; ++q) {
    #pragma unroll
    for (int n = 0; n < 4; ++n) {
      const int br = n * 16 + l15;
      bf16x8 b = *(const bf16x8*)(sXt + br * 512 + (((q + 4) * 64 + lhi * 16) ^ ((br & 7) << 4)));
      z[n] = __builtin_amdgcn_mfma_f32_16x16x32_bf16(ca[q], b, z[n], 0, 0, 0);
    }
  }

  // ---- row-lse + diag (row i = 16*wid + 4*lhi + r; col = 16n + l15) ----
  float partial = 0.f;
  #pragma unroll
  for (int r = 0; r < 4; ++r) {
    float m = fmaxf(fmaxf(z[0][r], z[1][r]), fmaxf(z[2][r], z[3][r]));
    #pragma unroll
    for (int d = 1; d < 16; d <<= 1) m = fmaxf(m, __shfl_xor(m, d));
    float s = __expf(z[0][r] - m) + __expf(z[1][r] - m) +
              __expf(z[2][r] - m) + __expf(z[3][r] - m);
    #pragma unroll
    for (int d = 1; d < 16; d <<= 1) s += __shfl_xor(s, d);
    const float lse = m + __logf(s);
    float dv = 0.f;
    #pragma unroll
    for (int n = 0; n < 4; ++n) dv = (n == wid) ? z[n][r] : dv;  // static idx
    if (l15 == lhi * 4 + r) partial += dv - lse;
  }
  #pragma unroll
  for (int d = 1; d < 64; d <<= 1) partial += __shfl_xor(partial, d);
  if (lane == 0) atomicAdd(out, partial * (1.0f / (B_ * T_)));
}

extern "C" void kernel_launch(void* const* d_in, const int* in_sizes, int n_in,
                              void* d_out, int out_size, void* d_ws, size_t ws_size,
                              hipStream_t stream) {
  const float* C  = (const float*)d_in[0];
  const float* X  = (const float*)d_in[1];
  const float* W  = (const float*)d_in[2];
  const float* bb = (const float*)d_in[3];
  unsigned short* Wb = (unsigned short*)d_ws;   // 256 KB bf16 W
  float* out = (float*)d_out;

  k_wcvt <<<dim3(128),  dim3(256), 0, stream>>>(W, Wb, out);
  k_fused<<<dim3(1024), dim3(256), 0, stream>>>(C, X, Wb, bb, out);
}

// Round 4
// 269.371 us; speedup vs baseline: 1.1045x; 1.1045x over previous
//
#include <hip/hip_runtime.h>

#define B_  64
#define T_  1024
#define FC_ 256
#define FX_ 512

typedef __bf16 bf16x8 __attribute__((ext_vector_type(8)));
typedef float  f32x4  __attribute__((ext_vector_type(4)));

__device__ __forceinline__ unsigned short f2bf(float f) {
  union { float f; unsigned int u; } v; v.f = f;
  unsigned int r = v.u + 0x7fffu + ((v.u >> 16) & 1u);  // RNE
  return (unsigned short)(r >> 16);
}
__device__ __forceinline__ unsigned int pk2(float lo, float hi) {
  return (unsigned int)f2bf(lo) | ((unsigned int)f2bf(hi) << 16);
}
__device__ __forceinline__ uint4 pk8(float4 a, float4 b) {
  uint4 p;
  p.x = pk2(a.x, a.y); p.y = pk2(a.z, a.w);
  p.z = pk2(b.x, b.y); p.w = pk2(b.z, b.w);
  return p;
}

// ---------------------------------------------------------------------------
// Prep: W f32 [256][512] -> bf16 ws; zero the scalar output.
// ---------------------------------------------------------------------------
__global__ void k_wcvt(const float* __restrict__ W, unsigned short* __restrict__ Wb,
                       float* __restrict__ out) {
  const int i = blockIdx.x * 256 + threadIdx.x;   // 32768 float4-groups
  float4 v = ((const float4*)W)[i];
  ushort4 h;
  h.x = f2bf(v.x); h.y = f2bf(v.y); h.z = f2bf(v.z); h.w = f2bf(v.w);
  ((ushort4*)Wb)[i] = h;
  if (i == 0) out[0] = 0.f;
}

// ---------------------------------------------------------------------------
// Fused, one block (512 thr / 8 waves) per t.  Phase-separated for MLP:
//  P0: burst-load ALL of X_t (16 float4/thread), cvt -> 64KB swizzled LDS.
//  P1: GEMM1 Xt = X_t W^T (+b later): 16 K-slices, W B-frags from L2 with
//      1-slice reg prefetch, no global/LDS interleave hazards. Wave w owns
//      Xt cols [32w, 32w+32).  acc[4][2].
//  P2: burst-issue C frags (waves 0-3), write Xt+bias -> sXt (overlays sX).
//  P3: GEMM2 Z = C_t Xt^T (waves 0-3) + row-lse + diag + atomicAdd.
// LDS 64KB -> 2 blocks/CU; 3 barriers total.
// ---------------------------------------------------------------------------
__global__ __launch_bounds__(512, 4)
void k_fused(const float* __restrict__ C, const float* __restrict__ X,
             const unsigned short* __restrict__ Wb, const float* __restrict__ bias,
             float* __restrict__ out)
{
  __shared__ __align__(16) char sMem[65536];
  char* sX  = sMem;   // 64 rows x 1024 B (bf16 X_t, swizzled)
  char* sXt = sMem;   // 64 rows x 512 B  (bf16 Xt_t, swizzled) — overlays sX

  const int t    = blockIdx.x;
  const int tid  = threadIdx.x;
  const int lane = tid & 63;
  const int wid  = tid >> 6;      // 0..7
  const int l15  = lane & 15;
  const int lhi  = lane >> 4;     // 0..3

  // ---------------- P0: stage all of X_t ----------------
  const int xrow = tid >> 3;                 // 0..63
  const int xg   = tid & 7;                  // 8 threads per row
  const float* xptr = X + ((size_t)xrow * T_ + t) * FX_ + xg * 8;

  float4 xv[16];
  #pragma unroll
  for (int q = 0; q < 8; ++q) {
    xv[2 * q]     = *(const float4*)(xptr + 64 * q);
    xv[2 * q + 1] = *(const float4*)(xptr + 64 * q + 4);
  }

  const float bv0 = bias[wid * 32 + l15];
  const float bv1 = bias[wid * 32 + 16 + l15];

  f32x4 acc[4][2];
  #pragma unroll
  for (int i = 0; i < 4; ++i)
    #pragma unroll
    for (int n2 = 0; n2 < 2; ++n2)
      #pragma unroll
      for (int r = 0; r < 4; ++r) acc[i][n2][r] = 0.f;

  const int xswz = (xrow & 7) << 4;
  #pragma unroll
  for (int q = 0; q < 8; ++q) {
    // f32 cols [xg*8 + 64q, +8) -> bf16 bytes [xg*16 + 128q, +16)
    *(uint4*)(sX + xrow * 1024 + ((xg * 16 + 128 * q) ^ xswz)) =
        pk8(xv[2 * q], xv[2 * q + 1]);
  }
  __syncthreads();

  // ---------------- P1: GEMM1 (K = 512, 16 slices of 32) ----------------
  const char* wrow = (const char*)Wb + (size_t)(wid * 32 + l15) * 1024 + lhi * 16;
  bf16x8 wc0 = *(const bf16x8*)(wrow);
  bf16x8 wc1 = *(const bf16x8*)(wrow + 16384);
  #pragma unroll
  for (int s = 0; s < 16; ++s) {
    bf16x8 wn0, wn1;
    if (s < 15) {
      wn0 = *(const bf16x8*)(wrow + (s + 1) * 64);
      wn1 = *(const bf16x8*)(wrow + 16384 + (s + 1) * 64);
    }
    bf16x8 afr[4];
    #pragma unroll
    for (int i = 0; i < 4; ++i) {
      const int ar = i * 16 + l15;
      afr[i] = *(const bf16x8*)(sX + ar * 1024 + ((s * 64 + lhi * 16) ^ ((ar & 7) << 4)));
    }
    #pragma unroll
    for (int i = 0; i < 4; ++i) {
      acc[i][0] = __builtin_amdgcn_mfma_f32_16x16x32_bf16(afr[i], wc0, acc[i][0], 0, 0, 0);
      acc[i][1] = __builtin_amdgcn_mfma_f32_16x16x32_bf16(afr[i], wc1, acc[i][1], 0, 0, 0);
    }
    if (s < 15) { wc0 = wn0; wc1 = wn1; }
  }
  __syncthreads();   // all sX reads done; region becomes sXt

  // ---------------- P2: burst C (waves 0-3) + Xt(+bias) -> sXt ----------------
  float4 cv[16];
  if (wid < 4) {
    const float* cptr = C + ((size_t)(wid * 16 + l15) * T_ + t) * FC_ + lhi * 8;
    #pragma unroll
    for (int s = 0; s < 8; ++s) {
      cv[2 * s]     = *(const float4*)(cptr + 32 * s);
      cv[2 * s + 1] = *(const float4*)(cptr + 32 * s + 4);
    }
  }

  {
    const int c0 = (wid * 32 + l15) * 2;
    const int c1 = (wid * 32 + 16 + l15) * 2;
    #pragma unroll
    for (int i = 0; i < 4; ++i)
      #pragma unroll
      for (int r = 0; r < 4; ++r) {
        const int j   = i * 16 + lhi * 4 + r;
        const int rsw = (j & 7) << 4;
        *(unsigned short*)(sXt + j * 512 + (c0 ^ rsw)) = f2bf(acc[i][0][r] + bv0);
        *(unsigned short*)(sXt + j * 512 + (c1 ^ rsw)) = f2bf(acc[i][1][r] + bv1);
      }
  }
  __syncthreads();

  // ---------------- P3: GEMM2 + lse (waves 0-3) ----------------
  if (wid < 4) {
    f32x4 z[4];
    #pragma unroll
    for (int n = 0; n < 4; ++n)
      #pragma unroll
      for (int r = 0; r < 4; ++r) z[n][r] = 0.f;

    #pragma unroll
    for (int s = 0; s < 8; ++s) {
      bf16x8 ca = __builtin_bit_cast(bf16x8, pk8(cv[2 * s], cv[2 * s + 1]));
      #pragma unroll
      for (int n = 0; n < 4; ++n) {
        const int br = n * 16 + l15;
        bf16x8 b = *(const bf16x8*)(sXt + br * 512 + ((s * 64 + lhi * 16) ^ ((br & 7) << 4)));
        z[n] = __builtin_amdgcn_mfma_f32_16x16x32_bf16(ca, b, z[n], 0, 0, 0);
      }
    }

    // row i = 16*wid + 4*lhi + r ; col j = 16n + l15
    float partial = 0.f;
    #pragma unroll
    for (int r = 0; r < 4; ++r) {
      float m = fmaxf(fmaxf(z[0][r], z[1][r]), fmaxf(z[2][r], z[3][r]));
      #pragma unroll
      for (int d = 1; d < 16; d <<= 1) m = fmaxf(m, __shfl_xor(m, d));
      float s = __expf(z[0][r] - m) + __expf(z[1][r] - m) +
                __expf(z[2][r] - m) + __expf(z[3][r] - m);
      #pragma unroll
      for (int d = 1; d < 16; d <<= 1) s += __shfl_xor(s, d);
      const float lse = m + __logf(s);
      float dv = 0.f;
      #pragma unroll
      for (int n = 0; n < 4; ++n) dv = (n == wid) ? z[n][r] : dv;  // static idx
      if (l15 == lhi * 4 + r) partial += dv - lse;
    }
    #pragma unroll
    for (int d = 1; d < 64; d <<= 1) partial += __shfl_xor(partial, d);
    if (lane == 0) atomicAdd(out, partial * (1.0f / (B_ * T_)));
  }
}

extern "C" void kernel_launch(void* const* d_in, const int* in_sizes, int n_in,
                              void* d_out, int out_size, void* d_ws, size_t ws_size,
                              hipStream_t stream) {
  const float* C  = (const float*)d_in[0];
  const float* X  = (const float*)d_in[1];
  const float* W  = (const float*)d_in[2];
  const float* bb = (const float*)d_in[3];
  unsigned short* Wb = (unsigned short*)d_ws;   // 256 KB bf16 W
  float* out = (float*)d_out;

  k_wcvt <<<dim3(128),  dim3(256), 0, stream>>>(W, Wb, out);
  k_fused<<<dim3(1024), dim3(512), 0, stream>>>(C, X, Wb, bb, out);
}